// Round 3
// baseline (103.645 us; speedup 1.0000x reference)
//
#include <hip/hip_runtime.h>
#include <hip/hip_bf16.h>

// Problem: B=64, P=128, D=1024  (all fp32)
//   s[b,p] = dot(concat(h[b,p],q[b,p]), W_att)   (+b_att uniform -> cancels in softmax)
//   a      = softmax_P(s)
//   out[b] = sum_p a[b,p] * dot(concat(h,q), W_fc) + b_fc
// Traffic floor: h+q = 64 MiB fp32 read once => ~10.6 us at 6.3 TB/s.

#define BB 64
#define PP 128
#define DD 1024
#define RR 4   // rows per block

// Stage 1: one block (256 thr) per 4 consecutive rows.
// Threads 0..127 cover the h-half, 128..255 the q-half; each thread owns two
// float4 chunks (j and j+128) of its 1024-float half. Weights are loaded into
// registers ONCE and reused across the 4 rows; all 8 row loads are issued
// before any FMA for max memory-level parallelism.
__global__ __launch_bounds__(256) void score_kernel(
    const float* __restrict__ h,
    const float* __restrict__ q,
    const float* __restrict__ Watt,
    const float* __restrict__ Wfc,
    float* __restrict__ s_out, float* __restrict__ t_out)
{
    const int tid = threadIdx.x;       // 0..255
    const bool isq = tid >= 128;
    const int j = tid & 127;           // float4-chunk lane within half
    const int r0 = blockIdx.x * RR;    // first row of this block

    const float4* base = (const float4*)(isq ? q : h) + (size_t)r0 * (DD / 4);
    const float4* wa4  = (const float4*)(Watt + (isq ? DD : 0));
    const float4* wf4  = (const float4*)(Wfc  + (isq ? DD : 0));

    // weights in registers, reused across RR rows
    const float4 a0 = wa4[j], a1 = wa4[j + 128];
    const float4 f0 = wf4[j], f1 = wf4[j + 128];

    // issue all row loads up front (8 x 16B per thread)
    float4 x[RR][2];
    #pragma unroll
    for (int rr = 0; rr < RR; ++rr) {
        const float4* row = base + rr * (DD / 4);
        x[rr][0] = row[j];
        x[rr][1] = row[j + 128];
    }

    float s_acc[RR], t_acc[RR];
    #pragma unroll
    for (int rr = 0; rr < RR; ++rr) {
        const float4 x0 = x[rr][0], x1 = x[rr][1];
        s_acc[rr] = x0.x*a0.x + x0.y*a0.y + x0.z*a0.z + x0.w*a0.w
                  + x1.x*a1.x + x1.y*a1.y + x1.z*a1.z + x1.w*a1.w;
        t_acc[rr] = x0.x*f0.x + x0.y*f0.y + x0.z*f0.z + x0.w*f0.w
                  + x1.x*f1.x + x1.y*f1.y + x1.z*f1.z + x1.w*f1.w;
    }

    // wave(64) shuffle reduce all 8 accumulators
    #pragma unroll
    for (int off = 32; off > 0; off >>= 1) {
        #pragma unroll
        for (int rr = 0; rr < RR; ++rr) {
            s_acc[rr] += __shfl_down(s_acc[rr], off, 64);
            t_acc[rr] += __shfl_down(t_acc[rr], off, 64);
        }
    }

    __shared__ float sh[4][2 * RR];
    const int wave = tid >> 6;
    if ((tid & 63) == 0) {
        #pragma unroll
        for (int rr = 0; rr < RR; ++rr) {
            sh[wave][rr]      = s_acc[rr];
            sh[wave][RR + rr] = t_acc[rr];
        }
    }
    __syncthreads();
    if (tid < 2 * RR) {
        const float v = sh[0][tid] + sh[1][tid] + sh[2][tid] + sh[3][tid];
        if (tid < RR) s_out[r0 + tid]      = v;
        else          t_out[r0 + tid - RR] = v;
    }
}

// Stage 2: one block per batch; softmax over P=128 + weighted pool.
__global__ __launch_bounds__(128) void softmax_pool_kernel(
    const float* __restrict__ s_in, const float* __restrict__ t_in,
    const float* __restrict__ b_fc,
    float* __restrict__ out)
{
    const int b = blockIdx.x;
    const int p = threadIdx.x;          // 0..127 (2 waves)
    const float s = s_in[b * PP + p];
    const float t = t_in[b * PP + p];

    // block max
    float m = s;
    #pragma unroll
    for (int off = 32; off > 0; off >>= 1) m = fmaxf(m, __shfl_down(m, off, 64));
    __shared__ float sh_m[2];
    if ((p & 63) == 0) sh_m[p >> 6] = m;
    __syncthreads();
    m = fmaxf(sh_m[0], sh_m[1]);

    float e   = __expf(s - m);
    float num = e * t;
    #pragma unroll
    for (int off = 32; off > 0; off >>= 1) {
        e   += __shfl_down(e, off, 64);
        num += __shfl_down(num, off, 64);
    }
    __shared__ float sh_z[2], sh_n[2];
    if ((p & 63) == 0) { sh_z[p >> 6] = e; sh_n[p >> 6] = num; }
    __syncthreads();
    if (p == 0) {
        const float Z = sh_z[0] + sh_z[1];
        const float N = sh_n[0] + sh_n[1];
        out[b] = N / Z + b_fc[0];
    }
}

extern "C" void kernel_launch(void* const* d_in, const int* in_sizes, int n_in,
                              void* d_out, int out_size, void* d_ws, size_t ws_size,
                              hipStream_t stream) {
    const float* h     = (const float*)d_in[0];
    const float* q     = (const float*)d_in[1];
    const float* W_att = (const float*)d_in[2];
    // d_in[3] = b_att (uniform across P -> cancels in softmax)
    const float* W_fc  = (const float*)d_in[4];
    const float* b_fc  = (const float*)d_in[5];

    float* s_ws = (float*)d_ws;                 // B*P floats
    float* t_ws = s_ws + BB * PP;               // B*P floats

    score_kernel<<<(BB * PP) / RR, 256, 0, stream>>>(h, q, W_att, W_fc, s_ws, t_ws);
    softmax_pool_kernel<<<BB, 128, 0, stream>>>(s_ws, t_ws, b_fc, (float*)d_out);
}